// Round 5
// baseline (540.009 us; speedup 1.0000x reference)
//
#include <hip/hip_runtime.h>
#include <hip/hip_bf16.h>

typedef float f32x4 __attribute__((ext_vector_type(4)));
typedef short s16x8 __attribute__((ext_vector_type(8)));

__device__ __forceinline__ unsigned short f32_to_bf16(float f){
    union { float f; unsigned u; } v; v.f = f;
    unsigned r = v.u + 0x7fffu + ((v.u >> 16) & 1u);   // RNE
    return (unsigned short)(r >> 16);
}
__device__ __forceinline__ unsigned pack2(float a, float b){
    float2 t; t.x = a; t.y = b;
    __hip_bfloat162 h = __float22bfloat162_rn(t);      // v_cvt_pk_bf16_f32
    union { __hip_bfloat162 h; unsigned u; } c; c.h = h;
    return c.u;
}

// LDS-only barrier: publishes DS ops without draining vmcnt (prefetch survives).
__device__ __forceinline__ void wg_barrier(){
    asm volatile("s_waitcnt lgkmcnt(0)" ::: "memory");
    __builtin_amdgcn_s_barrier();
    __builtin_amdgcn_sched_barrier(0);
}

// ---------- W pre-convert: wbf[w][d][c] = bf16(W[d][c] + (d==c)) -------------
__global__ __launch_bounds__(256)
void wconv_kernel(const float* __restrict__ W0p, const float* __restrict__ W0m,
                  const float* __restrict__ W1p, const float* __restrict__ W1m,
                  const float* __restrict__ W2p, const float* __restrict__ W2m,
                  unsigned short* __restrict__ wbf)
{
    const int idx = blockIdx.x * 256 + threadIdx.x;   // 384*256 = 98304
    const int w  = idx >> 14;
    const int rc = idx & 16383;
    const float* Wp;
    switch (w) {
        case 0: Wp = W0p; break;  case 1: Wp = W0m; break;
        case 2: Wp = W1p; break;  case 3: Wp = W1m; break;
        case 4: Wp = W2p; break;  default: Wp = W2m; break;
    }
    const float v = Wp[rc] + (((rc >> 7) == (rc & 127)) ? 1.0f : 0.0f);
    wbf[idx] = f32_to_bf16(v);
}

// ---------- l = 1,2: persistent, reg-prefetch, fence-free barriers -----------
template<int ML, int NT>
__global__ __launch_bounds__(256, 4)
void lx_pipe(const float* __restrict__ x, const unsigned short* __restrict__ wbf,
             float* __restrict__ out, int yoff0, int yoff1, int w0, int ntiles)
{
    constexpr int BLK   = 128 * ML;            // floats per node-block
    constexpr int RROWS = NT * ML;             // real rows: 40 / 24
    constexpr int RTC   = (RROWS + 15) / 16;   // MFMA row-tiles: 3 / 2
    constexpr int H     = (RTC + 1) / 2;       // tiles per wave-half: 2 / 1
    constexpr int LDSS  = 136;                 // bf16 elems per lin row (272 B)
    constexpr int QPT   = NT * 32 / 256;       // channel-quads per thread: 1
    constexpr int ITER  = NT * BLK / 1024;     // flush float4 iters: 5 / 3
    constexpr int IN_B  = RTC * 16 * LDSS * 2;
    constexpr int OUT_B = NT * BLK * 4;
    constexpr int SMEM  = OUT_B > IN_B ? OUT_B : IN_B;
    __shared__ __attribute__((aligned(16))) char smem[SMEM];
    unsigned short* lin  = (unsigned short*)smem;
    float*          lout = (float*)smem;

    const int parity = blockIdx.y;
    const int yoff   = parity ? yoff1 : yoff0;
    const unsigned short* wb = wbf + (size_t)(w0 + parity) * 16384;

    const int tid = threadIdx.x;
    const int wv  = tid >> 6, ln = tid & 63;
    const int l16 = ln & 15,  lhi = ln >> 4;
    const int th  = wv >> 1,  ch = wv & 1;
    const int t0  = th * H;

    // ---- B fragments (W^T+I): loaded ONCE per persistent WG (L2-resident)
    s16x8 bfr[4][4];
    #pragma unroll
    for (int s = 0; s < 4; ++s)
        #pragma unroll
        for (int tf = 0; tf < 4; ++tf)
            bfr[s][tf] = *reinterpret_cast<const s16x8*>(
                wb + (ch * 64 + tf * 16 + l16) * 128 + s * 32 + lhi * 8);

    float4 buf[QPT][ML];
    auto issue = [&](int t) {
        const float* src = x + yoff + (size_t)t * NT * 2304;
        #pragma unroll
        for (int i = 0; i < QPT; ++i) {
            const int q  = i * 256 + tid;
            const int nl = q >> 5;
            const int c4 = (q & 31) * 4;
            const float* p = src + (size_t)nl * 2304 + c4 * ML;
            #pragma unroll
            for (int j = 0; j < ML; ++j)
                buf[i][j] = *reinterpret_cast<const float4*>(p + j * 4);
        }
    };

    issue(blockIdx.x);   // prologue prefetch

    for (int tile = blockIdx.x; tile < ntiles; ) {
        const int next = tile + (int)gridDim.x;

        wg_barrier();    // prev flush's LDS reads done -> safe to overwrite lin

        // ---- pack buf -> lin (de-interleave + bf16)
        #pragma unroll
        for (int i = 0; i < QPT; ++i) {
            const int q  = i * 256 + tid;
            const int nl = q >> 5;
            const int c4 = (q & 31) * 4;
            float v[4 * ML];
            #pragma unroll
            for (int j = 0; j < ML; ++j) {
                v[j*4+0] = buf[i][j].x; v[j*4+1] = buf[i][j].y;
                v[j*4+2] = buf[i][j].z; v[j*4+3] = buf[i][j].w;
            }
            #pragma unroll
            for (int mm = 0; mm < ML; ++mm) {
                uint2 pk;
                pk.x = pack2(v[mm],        v[mm +   ML]);
                pk.y = pack2(v[mm + 2*ML], v[mm + 3*ML]);
                *reinterpret_cast<uint2*>(&lin[(nl * ML + mm) * LDSS + c4]) = pk;
            }
        }

        // ---- prefetch next tile (stays in flight across all barriers)
        if (next < ntiles) issue(next);

        wg_barrier();    // lin published

        // ---- MFMA
        f32x4 acc[H][4];
        #pragma unroll
        for (int rt = 0; rt < H; ++rt)
            #pragma unroll
            for (int tf = 0; tf < 4; ++tf) acc[rt][tf] = (f32x4){0.f,0.f,0.f,0.f};

        #pragma unroll
        for (int s = 0; s < 4; ++s) {
            const int k0 = s * 32 + lhi * 8;
            #pragma unroll
            for (int rt = 0; rt < H; ++rt) {
                if (t0 + rt < RTC) {
                    const s16x8 af = *reinterpret_cast<const s16x8*>(
                        &lin[((t0 + rt) * 16 + l16) * LDSS + k0]);
                    #pragma unroll
                    for (int tf = 0; tf < 4; ++tf)
                        acc[rt][tf] = __builtin_amdgcn_mfma_f32_16x16x32_bf16(
                            af, bfr[s][tf], acc[rt][tf], 0, 0, 0);
                }
            }
        }

        wg_barrier();    // lin dead -> lout may overwrite smem

        // ---- scatter acc -> lout in output (interleaved) layout
        #pragma unroll
        for (int rt = 0; rt < H; ++rt) {
            if (t0 + rt < RTC) {
                #pragma unroll
                for (int tf = 0; tf < 4; ++tf) {
                    const int col = ch * 64 + tf * 16 + l16;
                    #pragma unroll
                    for (int j = 0; j < 4; ++j) {
                        const int row = (t0 + rt) * 16 + lhi * 4 + j;
                        if (row < RROWS) {
                            const int nl = row / ML;
                            const int mm = row - nl * ML;
                            lout[nl * BLK + col * ML + mm] = acc[rt][tf][j];
                        }
                    }
                }
            }
        }

        wg_barrier();    // lout published

        // ---- flush: contiguous float4 stores (fire-and-forget)
        {
            float* dst = out + yoff + (size_t)tile * NT * 2304;
            #pragma unroll
            for (int i = 0; i < ITER; ++i) {
                const int f  = (i * 256 + tid) * 4;
                const int nl = f / BLK;
                const int rr = f - nl * BLK;
                *reinterpret_cast<float4*>(dst + (size_t)nl * 2304 + rr) =
                    *reinterpret_cast<const float4*>(&lout[f]);
            }
        }
        tile = next;
    }
}

// ---------- l = 0: persistent, operand-swapped, direct coalesced stores ------
__global__ __launch_bounds__(256, 4)
void l0_pipe(const float* __restrict__ x, const unsigned short* __restrict__ wbf,
             float* __restrict__ out, int ntiles)
{
    constexpr int LDSS = 264;                       // 528 B rows
    __shared__ __attribute__((aligned(16))) unsigned short lin[16 * LDSS];

    const int tid = threadIdx.x;
    const int wv  = tid >> 6, ln = tid & 63;
    const int l16 = ln & 15,  lhi = ln >> 4;
    const int b     = wv >> 1;            // parity (0e / 0o)
    const int dbase = (wv & 1) * 64;
    const unsigned short* wb = wbf + b * 16384;

    // A fragments (W^T+I): once per persistent WG
    s16x8 afr[4][4];
    #pragma unroll
    for (int s = 0; s < 4; ++s)
        #pragma unroll
        for (int dt = 0; dt < 4; ++dt)
            afr[s][dt] = *reinterpret_cast<const s16x8*>(
                wb + (dbase + dt * 16 + l16) * 128 + s * 32 + lhi * 8);

    float4 buf[4];
    auto issue = [&](int t) {
        const float* src = x + (size_t)t * 16 * 2304;
        #pragma unroll
        for (int i = 0; i < 4; ++i) {
            const int f  = i * 1024 + tid * 4;
            const int nl = f >> 8, c = f & 255;
            buf[i] = *reinterpret_cast<const float4*>(src + (size_t)nl * 2304 + c);
        }
    };

    issue(blockIdx.x);

    for (int tile = blockIdx.x; tile < ntiles; ) {
        const int next = tile + (int)gridDim.x;

        wg_barrier();    // prev MFMA's LDS reads done -> safe to overwrite lin

        #pragma unroll
        for (int i = 0; i < 4; ++i) {        // pack (convert-only, contiguous)
            const int f  = i * 1024 + tid * 4;
            const int nl = f >> 8, c = f & 255;
            uint2 p; p.x = pack2(buf[i].x, buf[i].y); p.y = pack2(buf[i].z, buf[i].w);
            *reinterpret_cast<uint2*>(&lin[nl * LDSS + c]) = p;
        }

        if (next < ntiles) issue(next);      // prefetch survives barriers

        wg_barrier();    // lin published

        f32x4 acc[4];
        #pragma unroll
        for (int dt = 0; dt < 4; ++dt) acc[dt] = (f32x4){0.f,0.f,0.f,0.f};

        #pragma unroll
        for (int s = 0; s < 4; ++s) {
            const s16x8 bfv = *reinterpret_cast<const s16x8*>(
                &lin[l16 * LDSS + b * 128 + s * 32 + lhi * 8]);
            #pragma unroll
            for (int dt = 0; dt < 4; ++dt)
                acc[dt] = __builtin_amdgcn_mfma_f32_16x16x32_bf16(
                    afr[s][dt], bfv, acc[dt], 0, 0, 0);
        }

        // direct stores: lane l16 = node, reg quad = 4 consecutive d
        float* dst = out + ((size_t)tile * 16 + l16) * 2304 + b * 128 + dbase + lhi * 4;
        #pragma unroll
        for (int dt = 0; dt < 4; ++dt) {
            float4 vv; vv.x = acc[dt][0]; vv.y = acc[dt][1];
                       vv.z = acc[dt][2]; vv.w = acc[dt][3];
            *reinterpret_cast<float4*>(dst + dt * 16) = vv;
        }
        tile = next;
    }
}

extern "C" void kernel_launch(void* const* d_in, const int* in_sizes, int n_in,
                              void* d_out, int out_size, void* d_ws, size_t ws_size,
                              hipStream_t stream) {
    const float* x   = (const float*)d_in[0];
    const float* W0p = (const float*)d_in[1];
    const float* W0m = (const float*)d_in[2];
    const float* W1p = (const float*)d_in[3];
    const float* W1m = (const float*)d_in[4];
    const float* W2p = (const float*)d_in[5];
    const float* W2m = (const float*)d_in[6];
    float* out = (float*)d_out;
    unsigned short* wbf = (unsigned short*)d_ws;   // 6*128*128 bf16 = 196.6 KB

    const int N = in_sizes[0] / 2304;   // 100000

    wconv_kernel<<<384, 256, 0, stream>>>(W0p, W0m, W1p, W1m, W2p, W2m, wbf);

    // block offsets (floats): 0e:0, 0o:128 | 1e:256, 1o:640 | 2e:1024, 2o:1664
    lx_pipe<5, 8><<<dim3(2048, 2), 256, 0, stream>>>(x, wbf, out, 1024, 1664, 4, N / 8);
    lx_pipe<3, 8><<<dim3(2048, 2), 256, 0, stream>>>(x, wbf, out, 256,  640,  2, N / 8);
    l0_pipe      <<<2048,          256, 0, stream>>>(x, wbf, out, N / 16);
}

// Round 6
// 434.047 us; speedup vs baseline: 1.2441x; 1.2441x over previous
//
#include <hip/hip_runtime.h>
#include <hip/hip_bf16.h>

typedef float f32x4 __attribute__((ext_vector_type(4)));
typedef short s16x8 __attribute__((ext_vector_type(8)));

__device__ __forceinline__ unsigned short f32_to_bf16(float f){
    union { float f; unsigned u; } v; v.f = f;
    unsigned r = v.u + 0x7fffu + ((v.u >> 16) & 1u);   // RNE
    return (unsigned short)(r >> 16);
}
__device__ __forceinline__ unsigned pack2(float a, float b){
    float2 t; t.x = a; t.y = b;
    __hip_bfloat162 h = __float22bfloat162_rn(t);      // v_cvt_pk_bf16_f32
    union { __hip_bfloat162 h; unsigned u; } c; c.h = h;
    return c.u;
}

template<int N> __device__ __forceinline__ void wait_vmcnt(){
    if constexpr (N == 0)       asm volatile("s_waitcnt vmcnt(0)"  ::: "memory");
    else if constexpr (N == 3)  asm volatile("s_waitcnt vmcnt(3)"  ::: "memory");
    else if constexpr (N == 4)  asm volatile("s_waitcnt vmcnt(4)"  ::: "memory");
    else if constexpr (N == 5)  asm volatile("s_waitcnt vmcnt(5)"  ::: "memory");
    else if constexpr (N == 6)  asm volatile("s_waitcnt vmcnt(6)"  ::: "memory");
    else if constexpr (N == 8)  asm volatile("s_waitcnt vmcnt(8)"  ::: "memory");
    else if constexpr (N == 10) asm volatile("s_waitcnt vmcnt(10)" ::: "memory");
    else static_assert(N == 0, "add wait case");
    __builtin_amdgcn_sched_barrier(0);
}

// LDS-publish barrier: waits DS ops only; vmcnt (DMA/stores) stays in flight.
__device__ __forceinline__ void bar_sync(){
    asm volatile("s_waitcnt lgkmcnt(0)" ::: "memory");
    __builtin_amdgcn_s_barrier();
    __builtin_amdgcn_sched_barrier(0);
}

// async global->LDS DMA, 16B per lane; lds dest must be wave-uniform base.
__device__ __forceinline__ void dma16(const float* g, float* l){
    __builtin_amdgcn_global_load_lds(
        (const __attribute__((address_space(1))) unsigned int*)g,
        (__attribute__((address_space(3))) unsigned int*)l, 16, 0, 0);
}

// ---------- W pre-convert: wbf[w][d][c] = bf16(W[d][c] + (d==c)) -------------
__global__ __launch_bounds__(256)
void wconv_kernel(const float* __restrict__ W0p, const float* __restrict__ W0m,
                  const float* __restrict__ W1p, const float* __restrict__ W1m,
                  const float* __restrict__ W2p, const float* __restrict__ W2m,
                  unsigned short* __restrict__ wbf)
{
    const int idx = blockIdx.x * 256 + threadIdx.x;   // 384*256 = 98304
    const int w  = idx >> 14;
    const int rc = idx & 16383;
    const float* Wp;
    switch (w) {
        case 0: Wp = W0p; break;  case 1: Wp = W0m; break;
        case 2: Wp = W1p; break;  case 3: Wp = W1m; break;
        case 4: Wp = W2p; break;  default: Wp = W2m; break;
    }
    const float v = Wp[rc] + (((rc >> 7) == (rc & 127)) ? 1.0f : 0.0f);
    wbf[idx] = f32_to_bf16(v);
}

// ---------- l = 1,2: DMA-staged fp32, double-buffered, counted vmcnt ---------
template<int ML, int NT, int WGS>
__global__ __launch_bounds__(256, 2)
void lx_dma(const float* __restrict__ x, const unsigned short* __restrict__ wbf,
            float* __restrict__ out, int yoff0, int yoff1, int w0, int ntiles)
{
    constexpr int BLK   = 128 * ML;          // dwords per node-block
    constexpr int NTB   = NT * BLK;          // dwords per tile
    constexpr int DI    = NTB * 4 / 4096;    // DMA instrs/thread: 5 / 3
    constexpr int SI    = DI;                // flush instrs/thread
    constexpr int RROWS = NT * ML;           // 40 / 24
    constexpr int RTC   = (RROWS + 15) / 16; // 3 / 2

    __shared__ __attribute__((aligned(16))) float lin[2][NTB];
    __shared__ __attribute__((aligned(16))) float lout[NTB];

    const int parity = blockIdx.y;
    const int yoff   = parity ? yoff1 : yoff0;
    const unsigned short* wb = wbf + (size_t)(w0 + parity) * 16384;

    const int tid = threadIdx.x;
    const int wv  = tid >> 6, ln = tid & 63;
    const int l16 = ln & 15,  lhi = ln >> 4;

    // B frags (W^T+I): once per persistent WG; 4-way col split -> 32 VGPR
    s16x8 bfr[4][2];
    #pragma unroll
    for (int s = 0; s < 4; ++s)
        #pragma unroll
        for (int tf = 0; tf < 2; ++tf)
            bfr[s][tf] = *reinterpret_cast<const s16x8*>(
                wb + (wv * 32 + tf * 16 + l16) * 128 + s * 32 + lhi * 8);

    // frag row bases (dwords into a tile buffer)
    int fbase[RTC];
    #pragma unroll
    for (int rt = 0; rt < RTC; ++rt) {
        const int row = rt * 16 + l16;
        const int nl  = row / ML;
        fbase[rt] = nl * BLK + (row - nl * ML);
    }

    auto dma_tile = [&](int t, int cur) {
        const float* gb = x + (size_t)t * NT * 2304 + yoff;
        float* lb = &lin[cur][0];
        #pragma unroll
        for (int j = 0; j < DI; ++j) {
            const int chunk = j * 4 + wv;
            const int dw = chunk * 256 + ln * 4;   // lane's dword idx in tile
            const int nl = dw / BLK;
            const int r  = dw - nl * BLK;
            dma16(gb + (size_t)nl * 2304 + r, lb + chunk * 256);
        }
    };
    auto flush_tile = [&](int t) {
        float* gb = out + (size_t)t * NT * 2304 + yoff;
        #pragma unroll
        for (int i = 0; i < SI; ++i) {
            const int dw = (i * 256 + tid) * 4;
            const int nl = dw / BLK;
            const int r  = dw - nl * BLK;
            *reinterpret_cast<float4*>(gb + (size_t)nl * 2304 + r) =
                *reinterpret_cast<const float4*>(&lout[dw]);
        }
    };

    const int tstart = blockIdx.x;
    int cur = 0, last = tstart;
    dma_tile(tstart, 0);
    if (tstart + WGS < ntiles) { dma_tile(tstart + WGS, 1); wait_vmcnt<DI>(); }
    else                       { wait_vmcnt<0>(); }
    bar_sync();

    bool first = true;
    for (int t = tstart; t < ntiles; t += WGS, cur ^= 1) {
        const bool has1 = (t + WGS)     < ntiles;
        const bool has2 = (t + 2 * WGS) < ntiles;

        // 1. fragments (stride-ML gather + cvt_pk) + MFMA
        f32x4 acc[RTC][2];
        #pragma unroll
        for (int rt = 0; rt < RTC; ++rt) {
            acc[rt][0] = (f32x4){0.f,0.f,0.f,0.f};
            acc[rt][1] = (f32x4){0.f,0.f,0.f,0.f};
        }
        const float* bp = &lin[cur][0];
        #pragma unroll
        for (int s = 0; s < 4; ++s) {
            const int ko = (s * 32 + lhi * 8) * ML;
            #pragma unroll
            for (int rt = 0; rt < RTC; ++rt) {
                float a[8];
                #pragma unroll
                for (int j = 0; j < 8; ++j) a[j] = bp[fbase[rt] + ko + j * ML];
                union { s16x8 v; unsigned u[4]; } af;
                af.u[0] = pack2(a[0], a[1]); af.u[1] = pack2(a[2], a[3]);
                af.u[2] = pack2(a[4], a[5]); af.u[3] = pack2(a[6], a[7]);
                acc[rt][0] = __builtin_amdgcn_mfma_f32_16x16x32_bf16(af.v, bfr[s][0], acc[rt][0], 0, 0, 0);
                acc[rt][1] = __builtin_amdgcn_mfma_f32_16x16x32_bf16(af.v, bfr[s][1], acc[rt][1], 0, 0, 0);
            }
        }

        // 2. flush previous tile's lout (contiguous float4 stores)
        if (!first) flush_tile(t - WGS);

        bar_sync();   // frag reads of buf[cur] + lout reads complete WG-wide

        // 4. scatter acc -> lout in output (interleaved) layout
        #pragma unroll
        for (int rt = 0; rt < RTC; ++rt)
            #pragma unroll
            for (int tf = 0; tf < 2; ++tf) {
                const int col = wv * 32 + tf * 16 + l16;
                #pragma unroll
                for (int j = 0; j < 4; ++j) {
                    const int row = rt * 16 + lhi * 4 + j;
                    if (row < RROWS) {
                        const int nl = row / ML;
                        lout[nl * BLK + col * ML + (row - nl * ML)] = acc[rt][tf][j];
                    }
                }
            }

        // 5. refill buf[cur] with tile t+2 (safe: barrier above)
        if (has2) dma_tile(t + 2 * WGS, cur);

        // 6. guarantee DMA(t+1) landed; flush stores / DMA(t+2) stay in flight
        if (has1) {
            if (first) { if (has2) wait_vmcnt<DI>();      else wait_vmcnt<0>();  }
            else       { if (has2) wait_vmcnt<SI + DI>(); else wait_vmcnt<SI>(); }
        }
        bar_sync();   // lout published; all waves' DMA(t+1) shares complete
        first = false;
        last  = t;
    }
    flush_tile(last);
}

// ---------- l = 0: DMA-staged (XOR-swizzled), operand-swapped, direct stores -
template<int WGS>
__global__ __launch_bounds__(256, 4)
void l0_dma(const float* __restrict__ x, const unsigned short* __restrict__ wbf,
            float* __restrict__ out, int ntiles)
{
    constexpr int NT = 16;
    constexpr int DI = 4;   // 16 KB / (256 thr * 16 B)
    constexpr int SI = 4;   // direct stores per thread

    __shared__ __attribute__((aligned(16))) float lin[2][NT * 256];

    const int tid = threadIdx.x;
    const int wv  = tid >> 6, ln = tid & 63;
    const int l16 = ln & 15,  lhi = ln >> 4;
    const int b     = wv >> 1;            // parity (0e / 0o)
    const int dbase = (wv & 1) * 64;
    const unsigned short* wb = wbf + b * 16384;

    // A frags (W^T+I): once per persistent WG
    s16x8 afr[4][4];
    #pragma unroll
    for (int s = 0; s < 4; ++s)
        #pragma unroll
        for (int dt = 0; dt < 4; ++dt)
            afr[s][dt] = *reinterpret_cast<const s16x8*>(
                wb + (dbase + dt * 16 + l16) * 128 + s * 32 + lhi * 8);

    auto dma_tile = [&](int t, int cur) {
        const float* gb = x + (size_t)t * NT * 2304;
        float* lb = &lin[cur][0];
        #pragma unroll
        for (int j = 0; j < DI; ++j) {
            const int chunk = j * 4 + wv;
            const int dw   = chunk * 256 + ln * 4;
            const int node = dw >> 8;
            const int r    = dw & 255;
            // inverse-swizzled source; read side applies the same XOR
            dma16(gb + (size_t)node * 2304 + (r ^ ((node & 7) << 2)), lb + chunk * 256);
        }
    };

    const int tstart = blockIdx.x;
    int cur = 0;
    dma_tile(tstart, 0);
    if (tstart + WGS < ntiles) { dma_tile(tstart + WGS, 1); wait_vmcnt<DI>(); }
    else                       { wait_vmcnt<0>(); }
    bar_sync();

    for (int t = tstart; t < ntiles; t += WGS, cur ^= 1) {
        const bool has1 = (t + WGS)     < ntiles;
        const bool has2 = (t + 2 * WGS) < ntiles;

        // fragments: swizzled b128 reads + cvt_pk; MFMA (A=W rows, B=x nodes)
        f32x4 acc[4];
        #pragma unroll
        for (int dt = 0; dt < 4; ++dt) acc[dt] = (f32x4){0.f,0.f,0.f,0.f};

        const float* bp = &lin[cur][0];
        const int nb = l16 * 256;
        const int sw = (l16 & 7) << 2;
        #pragma unroll
        for (int s = 0; s < 4; ++s) {
            const int c0 = b * 128 + s * 32 + lhi * 8;
            const float4 v0 = *reinterpret_cast<const float4*>(&bp[nb + ((c0    ) ^ sw)]);
            const float4 v1 = *reinterpret_cast<const float4*>(&bp[nb + ((c0 + 4) ^ sw)]);
            union { s16x8 v; unsigned u[4]; } bf;
            bf.u[0] = pack2(v0.x, v0.y); bf.u[1] = pack2(v0.z, v0.w);
            bf.u[2] = pack2(v1.x, v1.y); bf.u[3] = pack2(v1.z, v1.w);
            #pragma unroll
            for (int dt = 0; dt < 4; ++dt)
                acc[dt] = __builtin_amdgcn_mfma_f32_16x16x32_bf16(afr[s][dt], bf.v, acc[dt], 0, 0, 0);
        }

        bar_sync();   // all waves done reading buf[cur]

        // direct stores: lane l16 = node, reg quad = 4 consecutive d (full lines)
        float* dst = out + ((size_t)t * NT + l16) * 2304 + b * 128 + dbase + lhi * 4;
        #pragma unroll
        for (int dt = 0; dt < 4; ++dt) {
            float4 vv; vv.x = acc[dt][0]; vv.y = acc[dt][1];
                       vv.z = acc[dt][2]; vv.w = acc[dt][3];
            *reinterpret_cast<float4*>(dst + dt * 16) = vv;
        }

        if (has2) dma_tile(t + 2 * WGS, cur);
        if (has1) { if (has2) wait_vmcnt<SI + DI>(); else wait_vmcnt<SI>(); }
        bar_sync();
    }
}

extern "C" void kernel_launch(void* const* d_in, const int* in_sizes, int n_in,
                              void* d_out, int out_size, void* d_ws, size_t ws_size,
                              hipStream_t stream) {
    const float* x   = (const float*)d_in[0];
    const float* W0p = (const float*)d_in[1];
    const float* W0m = (const float*)d_in[2];
    const float* W1p = (const float*)d_in[3];
    const float* W1m = (const float*)d_in[4];
    const float* W2p = (const float*)d_in[5];
    const float* W2m = (const float*)d_in[6];
    float* out = (float*)d_out;
    unsigned short* wbf = (unsigned short*)d_ws;   // 6*128*128 bf16 = 196.6 KB

    const int N = in_sizes[0] / 2304;   // 100000

    wconv_kernel<<<384, 256, 0, stream>>>(W0p, W0m, W1p, W1m, W2p, W2m, wbf);

    // offsets (dwords): 0e:0, 0o:128 | 1e:256, 1o:640 | 2e:1024, 2o:1664
    lx_dma<5, 8, 256><<<dim3(256, 2), 256, 0, stream>>>(x, wbf, out, 1024, 1664, 4, N / 8);
    lx_dma<3, 8, 512><<<dim3(512, 2), 256, 0, stream>>>(x, wbf, out, 256,  640,  2, N / 8);
    l0_dma<1024>     <<<1024,         256, 0, stream>>>(x, wbf, out, N / 16);
}

// Round 7
// 399.610 us; speedup vs baseline: 1.3513x; 1.0862x over previous
//
#include <hip/hip_runtime.h>
#include <hip/hip_bf16.h>

typedef float f32x4 __attribute__((ext_vector_type(4)));
typedef short s16x8 __attribute__((ext_vector_type(8)));

__device__ __forceinline__ unsigned short f32_to_bf16(float f){
    union { float f; unsigned u; } v; v.f = f;
    unsigned r = v.u + 0x7fffu + ((v.u >> 16) & 1u);   // RNE
    return (unsigned short)(r >> 16);
}
__device__ __forceinline__ unsigned pack2(float a, float b){
    float2 t; t.x = a; t.y = b;
    __hip_bfloat162 h = __float22bfloat162_rn(t);      // v_cvt_pk_bf16_f32
    union { __hip_bfloat162 h; unsigned u; } c; c.h = h;
    return c.u;
}

template<int N> __device__ __forceinline__ void wait_vmcnt(){
    if constexpr (N == 0)       asm volatile("s_waitcnt vmcnt(0)"  ::: "memory");
    else if constexpr (N == 3)  asm volatile("s_waitcnt vmcnt(3)"  ::: "memory");
    else if constexpr (N == 4)  asm volatile("s_waitcnt vmcnt(4)"  ::: "memory");
    else if constexpr (N == 5)  asm volatile("s_waitcnt vmcnt(5)"  ::: "memory");
    else if constexpr (N == 8)  asm volatile("s_waitcnt vmcnt(8)"  ::: "memory");
    else static_assert(N == 0, "add wait case");
    __builtin_amdgcn_sched_barrier(0);
}

// LDS-publish barrier: waits DS ops only; vmcnt (DMA/stores) stays in flight.
__device__ __forceinline__ void bar_sync(){
    asm volatile("s_waitcnt lgkmcnt(0)" ::: "memory");
    __builtin_amdgcn_s_barrier();
    __builtin_amdgcn_sched_barrier(0);
}

// async global->LDS DMA, 16B per lane; lds dest wave-uniform base + lane*16.
__device__ __forceinline__ void dma16(const float* g, float* l){
    __builtin_amdgcn_global_load_lds(
        (const __attribute__((address_space(1))) unsigned int*)g,
        (__attribute__((address_space(3))) unsigned int*)l, 16, 0, 0);
}

// ---------- W pre-convert: wbf[w][d][c] = bf16(W[d][c] + (d==c)) -------------
__global__ __launch_bounds__(256)
void wconv_kernel(const float* __restrict__ W0p, const float* __restrict__ W0m,
                  const float* __restrict__ W1p, const float* __restrict__ W1m,
                  const float* __restrict__ W2p, const float* __restrict__ W2m,
                  unsigned short* __restrict__ wbf)
{
    const int idx = blockIdx.x * 256 + threadIdx.x;   // 384*256 = 98304
    const int w  = idx >> 14;
    const int rc = idx & 16383;
    const float* Wp;
    switch (w) {
        case 0: Wp = W0p; break;  case 1: Wp = W0m; break;
        case 2: Wp = W1p; break;  case 3: Wp = W1m; break;
        case 4: Wp = W2p; break;  default: Wp = W2m; break;
    }
    const float v = Wp[rc] + (((rc >> 7) == (rc & 127)) ? 1.0f : 0.0f);
    wbf[idx] = f32_to_bf16(v);
}

// ---------- l = 1,2: DMA staging + wide-op pack + single-lin pipeline --------
template<int ML, int NT>
__global__ __launch_bounds__(256, 3)
void lx_dma(const float* __restrict__ x, const unsigned short* __restrict__ wbf,
            float* __restrict__ out, int yoff0, int yoff1, int w0, int ntiles)
{
    constexpr int BLK   = 128 * ML;          // dwords per node-block (640 / 384)
    constexpr int NTB   = NT * BLK;          // dwords per tile (5120 / 3072)
    constexpr int DI    = NTB * 4 / 4096;    // DMA instrs/thread: 5 / 3
    constexpr int SI    = DI;                // flush instrs/thread
    constexpr int RROWS = NT * ML;           // 40 / 24
    constexpr int RTC   = (RROWS + 15) / 16; // 3 / 2
    constexpr int PR    = RTC * 16;          // padded rows: 48 / 32
    constexpr int LDSS  = 136;               // bf16 elems per lbf row (272 B)
    constexpr int CPT   = NTB / 256;         // pack dwords/thread: 20 / 12
    constexpr int V4    = CPT / 4;           // pack b128 reads: 5 / 3

    __shared__ __attribute__((aligned(16))) float          lin[NTB];
    __shared__ __attribute__((aligned(16))) unsigned short lbf[PR * LDSS];
    __shared__ __attribute__((aligned(16))) float          lout[NTB];

    const int parity = blockIdx.y;
    const int yoff   = parity ? yoff1 : yoff0;
    const unsigned short* wb = wbf + (size_t)(w0 + parity) * 16384;

    const int tid = threadIdx.x;
    const int wv  = tid >> 6, ln = tid & 63;
    const int l16 = ln & 15,  lhi = ln >> 4;

    // B frags (W^T+I): once per persistent WG; 4-way col split -> 32 VGPR
    s16x8 bfr[4][2];
    #pragma unroll
    for (int s = 0; s < 4; ++s)
        #pragma unroll
        for (int tf = 0; tf < 2; ++tf)
            bfr[s][tf] = *reinterpret_cast<const s16x8*>(
                wb + (wv * 32 + tf * 16 + l16) * 128 + s * 32 + lhi * 8);

    // pack mapping: 32 threads per node; thread owns 4 channels x all m
    const int pnl = tid >> 5;            // node 0..NT-1 (NT==8)
    const int pc0 = (tid & 31) * 4;      // first channel

    auto dma_tile = [&](int t) {
        const float* gb = x + (size_t)t * NT * 2304 + yoff;
        #pragma unroll
        for (int j = 0; j < DI; ++j) {
            const int chunk = j * 4 + wv;
            const int dw = chunk * 256 + ln * 4;   // lane's dword idx in tile
            const int nl = dw / BLK;
            const int r  = dw - nl * BLK;
            dma16(gb + (size_t)nl * 2304 + r, &lin[chunk * 256]);
        }
    };
    auto flush_tile = [&](int t) {
        float* gb = out + (size_t)t * NT * 2304 + yoff;
        #pragma unroll
        for (int i = 0; i < SI; ++i) {
            const int dw = (i * 256 + tid) * 4;
            const int nl = dw / BLK;
            const int r  = dw - nl * BLK;
            *reinterpret_cast<float4*>(gb + (size_t)nl * 2304 + r) =
                *reinterpret_cast<const float4*>(&lout[dw]);
        }
    };

    int t = blockIdx.x;
    dma_tile(t);
    wait_vmcnt<0>();
    bar_sync();

    while (true) {
        // ---- pack: lin (fp32 native) -> lbf (bf16 de-interleaved rows)
        {
            float v[CPT];
            const float* sp = &lin[pnl * BLK + pc0 * ML];
            #pragma unroll
            for (int i = 0; i < V4; ++i) {
                const float4 t4 = *reinterpret_cast<const float4*>(sp + i * 4);
                v[i*4+0] = t4.x; v[i*4+1] = t4.y; v[i*4+2] = t4.z; v[i*4+3] = t4.w;
            }
            #pragma unroll
            for (int mm = 0; mm < ML; ++mm) {
                unsigned* wp = reinterpret_cast<unsigned*>(&lbf[(pnl * ML + mm) * LDSS + pc0]);
                wp[0] = pack2(v[mm],          v[ML + mm]);
                wp[1] = pack2(v[2*ML + mm],   v[3*ML + mm]);
            }
        }
        bar_sync();                      // lbf published; lin free

        const int nx = t + (int)gridDim.x;
        if (nx < ntiles) dma_tile(nx);   // refill lin; lands during MFMA/flush

        // ---- MFMA from lbf (b128 frags)
        f32x4 acc[RTC][2];
        #pragma unroll
        for (int rt = 0; rt < RTC; ++rt) {
            acc[rt][0] = (f32x4){0.f,0.f,0.f,0.f};
            acc[rt][1] = (f32x4){0.f,0.f,0.f,0.f};
        }
        #pragma unroll
        for (int s = 0; s < 4; ++s) {
            const int k0 = s * 32 + lhi * 8;
            #pragma unroll
            for (int rt = 0; rt < RTC; ++rt) {
                const s16x8 af = *reinterpret_cast<const s16x8*>(
                    &lbf[(rt * 16 + l16) * LDSS + k0]);
                acc[rt][0] = __builtin_amdgcn_mfma_f32_16x16x32_bf16(af, bfr[s][0], acc[rt][0], 0, 0, 0);
                acc[rt][1] = __builtin_amdgcn_mfma_f32_16x16x32_bf16(af, bfr[s][1], acc[rt][1], 0, 0, 0);
            }
        }

        // ---- scatter acc -> lout in output (interleaved) layout
        #pragma unroll
        for (int rt = 0; rt < RTC; ++rt)
            #pragma unroll
            for (int tf = 0; tf < 2; ++tf) {
                const int col = wv * 32 + tf * 16 + l16;
                #pragma unroll
                for (int j = 0; j < 4; ++j) {
                    const int row = rt * 16 + lhi * 4 + j;
                    if (row < RROWS) {
                        const int nl = row / ML;
                        lout[nl * BLK + col * ML + (row - nl * ML)] = acc[rt][tf][j];
                    }
                }
            }
        bar_sync();                      // lout published; MFMA reads drained

        flush_tile(t);                   // fire-and-forget global stores

        if (nx >= ntiles) break;
        wait_vmcnt<SI>();                // in-order: DMA(nx) landed; <=SI stores in flight
        bar_sync();
        t = nx;
    }
}

// ---------- l = 0: DMA-staged (XOR-swizzled), operand-swapped, direct stores -
template<int WGS>
__global__ __launch_bounds__(256, 4)
void l0_dma(const float* __restrict__ x, const unsigned short* __restrict__ wbf,
            float* __restrict__ out, int ntiles)
{
    constexpr int NT = 16;
    constexpr int DI = 4;   // 16 KB / (256 thr * 16 B)
    constexpr int SI = 4;   // direct stores per thread

    __shared__ __attribute__((aligned(16))) float lin[2][NT * 256];

    const int tid = threadIdx.x;
    const int wv  = tid >> 6, ln = tid & 63;
    const int l16 = ln & 15,  lhi = ln >> 4;
    const int b     = wv >> 1;            // parity (0e / 0o)
    const int dbase = (wv & 1) * 64;
    const unsigned short* wb = wbf + b * 16384;

    // A frags (W^T+I): once per persistent WG
    s16x8 afr[4][4];
    #pragma unroll
    for (int s = 0; s < 4; ++s)
        #pragma unroll
        for (int dt = 0; dt < 4; ++dt)
            afr[s][dt] = *reinterpret_cast<const s16x8*>(
                wb + (dbase + dt * 16 + l16) * 128 + s * 32 + lhi * 8);

    auto dma_tile = [&](int t, int cur) {
        const float* gb = x + (size_t)t * NT * 2304;
        float* lb = &lin[cur][0];
        #pragma unroll
        for (int j = 0; j < DI; ++j) {
            const int chunk = j * 4 + wv;
            const int dw   = chunk * 256 + ln * 4;
            const int node = dw >> 8;
            const int r    = dw & 255;
            // inverse-swizzled source; read side applies the same XOR
            dma16(gb + (size_t)node * 2304 + (r ^ ((node & 7) << 2)), lb + chunk * 256);
        }
    };

    const int tstart = blockIdx.x;
    int cur = 0;
    dma_tile(tstart, 0);
    if (tstart + WGS < ntiles) { dma_tile(tstart + WGS, 1); wait_vmcnt<DI>(); }
    else                       { wait_vmcnt<0>(); }
    bar_sync();

    for (int t = tstart; t < ntiles; t += WGS, cur ^= 1) {
        const bool has1 = (t + WGS)     < ntiles;
        const bool has2 = (t + 2 * WGS) < ntiles;

        // fragments: swizzled b128 reads + cvt_pk; MFMA (A=W rows, B=x nodes)
        f32x4 acc[4];
        #pragma unroll
        for (int dt = 0; dt < 4; ++dt) acc[dt] = (f32x4){0.f,0.f,0.f,0.f};

        const float* bp = &lin[cur][0];
        const int nb = l16 * 256;
        const int sw = (l16 & 7) << 2;
        #pragma unroll
        for (int s = 0; s < 4; ++s) {
            const int c0 = b * 128 + s * 32 + lhi * 8;
            const float4 v0 = *reinterpret_cast<const float4*>(&bp[nb + ((c0    ) ^ sw)]);
            const float4 v1 = *reinterpret_cast<const float4*>(&bp[nb + ((c0 + 4) ^ sw)]);
            union { s16x8 v; unsigned u[4]; } bf;
            bf.u[0] = pack2(v0.x, v0.y); bf.u[1] = pack2(v0.z, v0.w);
            bf.u[2] = pack2(v1.x, v1.y); bf.u[3] = pack2(v1.z, v1.w);
            #pragma unroll
            for (int dt = 0; dt < 4; ++dt)
                acc[dt] = __builtin_amdgcn_mfma_f32_16x16x32_bf16(afr[s][dt], bf.v, acc[dt], 0, 0, 0);
        }

        bar_sync();   // all waves done reading buf[cur]

        // direct stores: lane l16 = node, reg quad = 4 consecutive d (full lines)
        float* dst = out + ((size_t)t * NT + l16) * 2304 + b * 128 + dbase + lhi * 4;
        #pragma unroll
        for (int dt = 0; dt < 4; ++dt) {
            float4 vv; vv.x = acc[dt][0]; vv.y = acc[dt][1];
                       vv.z = acc[dt][2]; vv.w = acc[dt][3];
            *reinterpret_cast<float4*>(dst + dt * 16) = vv;
        }

        if (has2) dma_tile(t + 2 * WGS, cur);
        if (has1) { if (has2) wait_vmcnt<SI + DI>(); else wait_vmcnt<SI>(); }
        bar_sync();
    }
}

extern "C" void kernel_launch(void* const* d_in, const int* in_sizes, int n_in,
                              void* d_out, int out_size, void* d_ws, size_t ws_size,
                              hipStream_t stream) {
    const float* x   = (const float*)d_in[0];
    const float* W0p = (const float*)d_in[1];
    const float* W0m = (const float*)d_in[2];
    const float* W1p = (const float*)d_in[3];
    const float* W1m = (const float*)d_in[4];
    const float* W2p = (const float*)d_in[5];
    const float* W2m = (const float*)d_in[6];
    float* out = (float*)d_out;
    unsigned short* wbf = (unsigned short*)d_ws;   // 6*128*128 bf16 = 196.6 KB

    const int N = in_sizes[0] / 2304;   // 100000

    wconv_kernel<<<384, 256, 0, stream>>>(W0p, W0m, W1p, W1m, W2p, W2m, wbf);

    // offsets (dwords): 0e:0, 0o:128 | 1e:256, 1o:640 | 2e:1024, 2o:1664
    lx_dma<5, 8><<<dim3(384, 2), 256, 0, stream>>>(x, wbf, out, 1024, 1664, 4, N / 8);
    lx_dma<3, 8><<<dim3(384, 2), 256, 0, stream>>>(x, wbf, out, 256,  640,  2, N / 8);
    l0_dma<1024><<<1024,         256, 0, stream>>>(x, wbf, out, N / 16);
}

// Round 8
// 390.136 us; speedup vs baseline: 1.3842x; 1.0243x over previous
//
#include <hip/hip_runtime.h>
#include <hip/hip_bf16.h>

typedef float f32x4 __attribute__((ext_vector_type(4)));
typedef short s16x8 __attribute__((ext_vector_type(8)));

__device__ __forceinline__ unsigned short f32_to_bf16(float f){
    union { float f; unsigned u; } v; v.f = f;
    unsigned r = v.u + 0x7fffu + ((v.u >> 16) & 1u);   // RNE
    return (unsigned short)(r >> 16);
}
__device__ __forceinline__ unsigned pack2(float a, float b){
    float2 t; t.x = a; t.y = b;
    __hip_bfloat162 h = __float22bfloat162_rn(t);      // v_cvt_pk_bf16_f32
    union { __hip_bfloat162 h; unsigned u; } c; c.h = h;
    return c.u;
}

template<int N> __device__ __forceinline__ void wait_vmcnt(){
    if constexpr (N == 0)       asm volatile("s_waitcnt vmcnt(0)"  ::: "memory");
    else if constexpr (N == 3)  asm volatile("s_waitcnt vmcnt(3)"  ::: "memory");
    else if constexpr (N == 4)  asm volatile("s_waitcnt vmcnt(4)"  ::: "memory");
    else if constexpr (N == 5)  asm volatile("s_waitcnt vmcnt(5)"  ::: "memory");
    else if constexpr (N == 8)  asm volatile("s_waitcnt vmcnt(8)"  ::: "memory");
    else if constexpr (N == 9)  asm volatile("s_waitcnt vmcnt(9)"  ::: "memory");
    else if constexpr (N == 15) asm volatile("s_waitcnt vmcnt(15)" ::: "memory");
    else static_assert(N == 0, "add wait case");
    __builtin_amdgcn_sched_barrier(0);
}

// LDS-publish barrier: waits DS ops only; vmcnt (DMA/stores) stays in flight.
__device__ __forceinline__ void bar_sync(){
    asm volatile("s_waitcnt lgkmcnt(0)" ::: "memory");
    __builtin_amdgcn_s_barrier();
    __builtin_amdgcn_sched_barrier(0);
}

// async global->LDS DMA, 16B per lane; lds dest wave-uniform base + lane*16.
__device__ __forceinline__ void dma16(const float* g, float* l){
    __builtin_amdgcn_global_load_lds(
        (const __attribute__((address_space(1))) unsigned int*)g,
        (__attribute__((address_space(3))) unsigned int*)l, 16, 0, 0);
}

// ---------- W pre-convert: wbf[w][d][c] = bf16(W[d][c] + (d==c)) -------------
__global__ __launch_bounds__(256)
void wconv_kernel(const float* __restrict__ W0p, const float* __restrict__ W0m,
                  const float* __restrict__ W1p, const float* __restrict__ W1m,
                  const float* __restrict__ W2p, const float* __restrict__ W2m,
                  unsigned short* __restrict__ wbf)
{
    const int idx = blockIdx.x * 256 + threadIdx.x;   // 384*256 = 98304
    const int w  = idx >> 14;
    const int rc = idx & 16383;
    const float* Wp;
    switch (w) {
        case 0: Wp = W0p; break;  case 1: Wp = W0m; break;
        case 2: Wp = W1p; break;  case 3: Wp = W1m; break;
        case 4: Wp = W2p; break;  default: Wp = W2m; break;
    }
    const float v = Wp[rc] + (((rc >> 7) == (rc & 127)) ? 1.0f : 0.0f);
    wbf[idx] = f32_to_bf16(v);
}

// ---------- l = 1,2: depth-2 DMA pipeline + wide-op pack ---------------------
template<int ML, int NT, int OCC>
__global__ __launch_bounds__(256, OCC)
void lx_dma(const float* __restrict__ x, const unsigned short* __restrict__ wbf,
            float* __restrict__ out, int yoff0, int yoff1, int w0, int ntiles)
{
    constexpr int BLK   = 128 * ML;          // dwords per node-block (640 / 384)
    constexpr int NTB   = NT * BLK;          // dwords per tile (5120 / 3072)
    constexpr int DI    = NTB * 4 / 4096;    // DMA instrs/thread: 5 / 3
    constexpr int SI    = DI;                // flush instrs/thread
    constexpr int RROWS = NT * ML;           // 40 / 24
    constexpr int RTC   = (RROWS + 15) / 16; // 3 / 2
    constexpr int PR    = RTC * 16;          // padded rows: 48 / 32
    constexpr int LDSS  = 136;               // bf16 elems per lbf row (272 B)
    constexpr int CPT   = NTB / 256;         // pack dwords/thread: 20 / 12
    constexpr int V4    = CPT / 4;           // pack b128 reads: 5 / 3

    __shared__ __attribute__((aligned(16))) float          lin[2][NTB];
    __shared__ __attribute__((aligned(16))) unsigned short lbf[PR * LDSS];
    __shared__ __attribute__((aligned(16))) float          lout[NTB];

    const int parity = blockIdx.y;
    const int yoff   = parity ? yoff1 : yoff0;
    const unsigned short* wb = wbf + (size_t)(w0 + parity) * 16384;

    const int tid = threadIdx.x;
    const int wv  = tid >> 6, ln = tid & 63;
    const int l16 = ln & 15,  lhi = ln >> 4;

    // B frags (W^T+I): once per persistent WG; 4-way col split -> 32 VGPR
    s16x8 bfr[4][2];
    #pragma unroll
    for (int s = 0; s < 4; ++s)
        #pragma unroll
        for (int tf = 0; tf < 2; ++tf)
            bfr[s][tf] = *reinterpret_cast<const s16x8*>(
                wb + (wv * 32 + tf * 16 + l16) * 128 + s * 32 + lhi * 8);

    // pack mapping: 32 threads per node; thread owns 4 channels x all m
    const int pnl = tid >> 5;            // node 0..NT-1 (NT==8)
    const int pc0 = (tid & 31) * 4;      // first channel

    auto dma_tile = [&](int t, int cur) {
        const float* gb = x + (size_t)t * NT * 2304 + yoff;
        #pragma unroll
        for (int j = 0; j < DI; ++j) {
            const int chunk = j * 4 + wv;
            const int dw = chunk * 256 + ln * 4;   // lane's dword idx in tile
            const int nl = dw / BLK;
            const int r  = dw - nl * BLK;
            dma16(gb + (size_t)nl * 2304 + r, &lin[cur][chunk * 256]);
        }
    };
    auto flush_tile = [&](int t) {
        float* gb = out + (size_t)t * NT * 2304 + yoff;
        #pragma unroll
        for (int i = 0; i < SI; ++i) {
            const int dw = (i * 256 + tid) * 4;
            const int nl = dw / BLK;
            const int r  = dw - nl * BLK;
            *reinterpret_cast<float4*>(gb + (size_t)nl * 2304 + r) =
                *reinterpret_cast<const float4*>(&lout[dw]);
        }
    };

    const int G = (int)gridDim.x;
    int t = blockIdx.x, cur = 0;
    dma_tile(t, 0);
    if (t + G < ntiles) { dma_tile(t + G, 1); wait_vmcnt<DI>(); }
    else                { wait_vmcnt<0>(); }
    bar_sync();

    while (true) {
        // ---- pack: lin[cur] (fp32 native) -> lbf (bf16 de-interleaved rows)
        {
            float v[CPT];
            const float* sp = &lin[cur][pnl * BLK + pc0 * ML];
            #pragma unroll
            for (int i = 0; i < V4; ++i) {
                const float4 t4 = *reinterpret_cast<const float4*>(sp + i * 4);
                v[i*4+0] = t4.x; v[i*4+1] = t4.y; v[i*4+2] = t4.z; v[i*4+3] = t4.w;
            }
            #pragma unroll
            for (int mm = 0; mm < ML; ++mm) {
                unsigned* wp = reinterpret_cast<unsigned*>(&lbf[(pnl * ML + mm) * LDSS + pc0]);
                wp[0] = pack2(v[mm],          v[ML + mm]);
                wp[1] = pack2(v[2*ML + mm],   v[3*ML + mm]);
            }
        }
        bar_sync();                      // lbf published; lin[cur] free

        if (t + 2 * G < ntiles) dma_tile(t + 2 * G, cur);   // depth-2 refill

        // ---- MFMA from lbf (b128 frags)
        f32x4 acc[RTC][2];
        #pragma unroll
        for (int rt = 0; rt < RTC; ++rt) {
            acc[rt][0] = (f32x4){0.f,0.f,0.f,0.f};
            acc[rt][1] = (f32x4){0.f,0.f,0.f,0.f};
        }
        #pragma unroll
        for (int s = 0; s < 4; ++s) {
            const int k0 = s * 32 + lhi * 8;
            #pragma unroll
            for (int rt = 0; rt < RTC; ++rt) {
                const s16x8 af = *reinterpret_cast<const s16x8*>(
                    &lbf[(rt * 16 + l16) * LDSS + k0]);
                acc[rt][0] = __builtin_amdgcn_mfma_f32_16x16x32_bf16(af, bfr[s][0], acc[rt][0], 0, 0, 0);
                acc[rt][1] = __builtin_amdgcn_mfma_f32_16x16x32_bf16(af, bfr[s][1], acc[rt][1], 0, 0, 0);
            }
        }

        // ---- scatter acc -> lout in output (interleaved) layout
        #pragma unroll
        for (int rt = 0; rt < RTC; ++rt)
            #pragma unroll
            for (int tf = 0; tf < 2; ++tf) {
                const int col = wv * 32 + tf * 16 + l16;
                #pragma unroll
                for (int j = 0; j < 4; ++j) {
                    const int row = rt * 16 + lhi * 4 + j;
                    if (row < RROWS) {
                        const int nl = row / ML;
                        lout[nl * BLK + col * ML + (row - nl * ML)] = acc[rt][tf][j];
                    }
                }
            }
        bar_sync();                      // lout published; lbf reads drained

        flush_tile(t);                   // fire-and-forget global stores

        if (t + G >= ntiles) break;
        // newest in flight: flush(t)[SI] + dma(t+2G)[DI] + flush(t-G)[SI];
        // DMA(t+G) is older -> retired after this wait (in-order vmcnt).
        wait_vmcnt<2 * SI + DI>();
        bar_sync();
        t += G; cur ^= 1;
    }
}

// ---------- l = 0: DMA-staged (XOR-swizzled), operand-swapped, direct stores -
template<int WGS>
__global__ __launch_bounds__(256, 4)
void l0_dma(const float* __restrict__ x, const unsigned short* __restrict__ wbf,
            float* __restrict__ out, int ntiles)
{
    constexpr int NT = 16;
    constexpr int DI = 4;   // 16 KB / (256 thr * 16 B)
    constexpr int SI = 4;   // direct stores per thread

    __shared__ __attribute__((aligned(16))) float lin[2][NT * 256];

    const int tid = threadIdx.x;
    const int wv  = tid >> 6, ln = tid & 63;
    const int l16 = ln & 15,  lhi = ln >> 4;
    const int b     = wv >> 1;            // parity (0e / 0o)
    const int dbase = (wv & 1) * 64;
    const unsigned short* wb = wbf + b * 16384;

    // A frags (W^T+I): once per persistent WG
    s16x8 afr[4][4];
    #pragma unroll
    for (int s = 0; s < 4; ++s)
        #pragma unroll
        for (int dt = 0; dt < 4; ++dt)
            afr[s][dt] = *reinterpret_cast<const s16x8*>(
                wb + (dbase + dt * 16 + l16) * 128 + s * 32 + lhi * 8);

    auto dma_tile = [&](int t, int cur) {
        const float* gb = x + (size_t)t * NT * 2304;
        float* lb = &lin[cur][0];
        #pragma unroll
        for (int j = 0; j < DI; ++j) {
            const int chunk = j * 4 + wv;
            const int dw   = chunk * 256 + ln * 4;
            const int node = dw >> 8;
            const int r    = dw & 255;
            // inverse-swizzled source; read side applies the same XOR
            dma16(gb + (size_t)node * 2304 + (r ^ ((node & 7) << 2)), lb + chunk * 256);
        }
    };

    const int tstart = blockIdx.x;
    int cur = 0;
    dma_tile(tstart, 0);
    if (tstart + WGS < ntiles) { dma_tile(tstart + WGS, 1); wait_vmcnt<4>(); }
    else                       { wait_vmcnt<0>(); }
    bar_sync();

    for (int t = tstart; t < ntiles; t += WGS, cur ^= 1) {
        const bool has1 = (t + WGS)     < ntiles;
        const bool has2 = (t + 2 * WGS) < ntiles;

        // fragments: swizzled b128 reads + cvt_pk; MFMA (A=W rows, B=x nodes)
        f32x4 acc[4];
        #pragma unroll
        for (int dt = 0; dt < 4; ++dt) acc[dt] = (f32x4){0.f,0.f,0.f,0.f};

        const float* bp = &lin[cur][0];
        const int nb = l16 * 256;
        const int sw = (l16 & 7) << 2;
        #pragma unroll
        for (int s = 0; s < 4; ++s) {
            const int c0 = b * 128 + s * 32 + lhi * 8;
            const float4 v0 = *reinterpret_cast<const float4*>(&bp[nb + ((c0    ) ^ sw)]);
            const float4 v1 = *reinterpret_cast<const float4*>(&bp[nb + ((c0 + 4) ^ sw)]);
            union { s16x8 v; unsigned u[4]; } bf;
            bf.u[0] = pack2(v0.x, v0.y); bf.u[1] = pack2(v0.z, v0.w);
            bf.u[2] = pack2(v1.x, v1.y); bf.u[3] = pack2(v1.z, v1.w);
            #pragma unroll
            for (int dt = 0; dt < 4; ++dt)
                acc[dt] = __builtin_amdgcn_mfma_f32_16x16x32_bf16(afr[s][dt], bf.v, acc[dt], 0, 0, 0);
        }

        bar_sync();   // all waves done reading buf[cur]

        // direct stores: lane l16 = node, reg quad = 4 consecutive d (full lines)
        float* dst = out + ((size_t)t * NT + l16) * 2304 + b * 128 + dbase + lhi * 4;
        #pragma unroll
        for (int dt = 0; dt < 4; ++dt) {
            float4 vv; vv.x = acc[dt][0]; vv.y = acc[dt][1];
                       vv.z = acc[dt][2]; vv.w = acc[dt][3];
            *reinterpret_cast<float4*>(dst + dt * 16) = vv;
        }

        if (has2) dma_tile(t + 2 * WGS, cur);
        if (has1) { if (has2) wait_vmcnt<8>(); else wait_vmcnt<4>(); }
        bar_sync();
    }
}

extern "C" void kernel_launch(void* const* d_in, const int* in_sizes, int n_in,
                              void* d_out, int out_size, void* d_ws, size_t ws_size,
                              hipStream_t stream) {
    const float* x   = (const float*)d_in[0];
    const float* W0p = (const float*)d_in[1];
    const float* W0m = (const float*)d_in[2];
    const float* W1p = (const float*)d_in[3];
    const float* W1m = (const float*)d_in[4];
    const float* W2p = (const float*)d_in[5];
    const float* W2m = (const float*)d_in[6];
    float* out = (float*)d_out;
    unsigned short* wbf = (unsigned short*)d_ws;   // 6*128*128 bf16 = 196.6 KB

    const int N = in_sizes[0] / 2304;   // 100000

    wconv_kernel<<<384, 256, 0, stream>>>(W0p, W0m, W1p, W1m, W2p, W2m, wbf);

    // offsets (dwords): 0e:0, 0o:128 | 1e:256, 1o:640 | 2e:1024, 2o:1664
    // lx5: 73 KB LDS -> 2 WG/CU; lx3: 44.5 KB -> 3 WG/CU; depth-2 pipeline.
    lx_dma<5, 8, 2><<<dim3(256, 2), 256, 0, stream>>>(x, wbf, out, 1024, 1664, 4, N / 8);
    lx_dma<3, 8, 3><<<dim3(384, 2), 256, 0, stream>>>(x, wbf, out, 256,  640,  2, N / 8);
    l0_dma<1024>   <<<1024,         256, 0, stream>>>(x, wbf, out, N / 16);
}